// Round 1
// baseline (576.792 us; speedup 1.0000x reference)
//
#include <hip/hip_runtime.h>

// Problem constants (B=1)
#define L_SEQ 4096
#define C_DIM 1024
#define H_NUM 16
#define D_HEAD 64

typedef __bf16 bf16x8 __attribute__((ext_vector_type(8)));
typedef __bf16 bf16x4 __attribute__((ext_vector_type(4)));
typedef float f32x4 __attribute__((ext_vector_type(4)));

#define AS1 __attribute__((address_space(1)))
#define AS3 __attribute__((address_space(3)))

__device__ inline __bf16 f2bf(float f) {
  unsigned u = __builtin_bit_cast(unsigned, f);
  u = (u + 0x7fffu + ((u >> 16) & 1u)) >> 16;
  unsigned short s = (unsigned short)u;
  return __builtin_bit_cast(__bf16, s);
}

__device__ inline void gload_lds16(const __bf16* g, __bf16* l) {
  // width-16 async global->LDS; LDS dest is wave-uniform base + lane*16
  __builtin_amdgcn_global_load_lds((const AS1 void*)g, (AS3 void*)l, 16, 0, 0);
}

// ---------------- x fp32 -> bf16 ----------------
__global__ __launch_bounds__(256) void cvt_f32_bf16(const float* __restrict__ in,
                                                    __bf16* __restrict__ out) {
  int i = (blockIdx.x * 256 + threadIdx.x) * 4;
  float4 v = *(const float4*)(in + i);
  bf16x4 o = {f2bf(v.x), f2bf(v.y), f2bf(v.z), f2bf(v.w)};
  *(bf16x4*)(out + i) = o;
}

// ---------------- W (K x N) fp32 -> Wt (N x K) bf16 ----------------
__global__ __launch_bounds__(256) void transpose_cvt(const float* __restrict__ W,
                                                     __bf16* __restrict__ Wt) {
  __shared__ float t[32][33];
  const int tx = threadIdx.x, ty = threadIdx.y;
  const int c0 = blockIdx.x * 32, r0 = blockIdx.y * 32;
#pragma unroll
  for (int k = 0; k < 4; ++k)
    t[ty + k * 8][tx] = W[(size_t)(r0 + ty + k * 8) * C_DIM + c0 + tx];
  __syncthreads();
#pragma unroll
  for (int k = 0; k < 4; ++k)
    Wt[(size_t)(c0 + ty + k * 8) * C_DIM + r0 + tx] = f2bf(t[tx][ty + k * 8]);
}

// ---------------- GEMM: C(MxN) = A(MxK,bf16) * Bt(NxK,bf16)^T ----------------
// 128x128 tile, BK=32, 256 threads = 4 waves (2x2), 16x16x32 bf16 MFMA.
template <bool OUT_BF16>
__global__ __launch_bounds__(256) void gemm_bt(const __bf16* __restrict__ A,
                                               const __bf16* __restrict__ Bt,
                                               void* __restrict__ Cp,
                                               int M, int N, int K) {
  __shared__ __bf16 As[128 * 32];
  __shared__ __bf16 Bs[128 * 32];
  const int tid = threadIdx.x;
  const int lane = tid & 63;
  const int wave = tid >> 6;
  const int wm = wave >> 1, wn = wave & 1;
  const int c16 = lane & 15, g4 = lane >> 4;
  const int srow = lane >> 2, scol = (lane & 3) * 8;

  f32x4 acc[4][4] = {};

  const size_t arow0 = (size_t)blockIdx.x * 128;
  const size_t brow0 = (size_t)blockIdx.y * 128;

  for (int kt = 0; kt < K; kt += 32) {
#pragma unroll
    for (int i = 0; i < 2; ++i) {
      const int row = i * 64 + wave * 16 + srow;
      gload_lds16(A + (arow0 + row) * K + kt + scol, As + (i * 64 + wave * 16) * 32);
      gload_lds16(Bt + (brow0 + row) * K + kt + scol, Bs + (i * 64 + wave * 16) * 32);
    }
    __syncthreads();
    bf16x8 af[4], bfr[4];
#pragma unroll
    for (int mi = 0; mi < 4; ++mi)
      af[mi] = *(const bf16x8*)(As + (wm * 64 + mi * 16 + c16) * 32 + g4 * 8);
#pragma unroll
    for (int ni = 0; ni < 4; ++ni)
      bfr[ni] = *(const bf16x8*)(Bs + (wn * 64 + ni * 16 + c16) * 32 + g4 * 8);
#pragma unroll
    for (int mi = 0; mi < 4; ++mi)
#pragma unroll
      for (int ni = 0; ni < 4; ++ni)
        acc[mi][ni] = __builtin_amdgcn_mfma_f32_16x16x32_bf16(af[mi], bfr[ni], acc[mi][ni], 0, 0, 0);
    __syncthreads();
  }

#pragma unroll
  for (int mi = 0; mi < 4; ++mi)
#pragma unroll
    for (int ni = 0; ni < 4; ++ni)
#pragma unroll
      for (int i = 0; i < 4; ++i) {
        size_t row = arow0 + wm * 64 + mi * 16 + g4 * 4 + i;
        size_t col = brow0 + wn * 64 + ni * 16 + c16;
        if (OUT_BF16)
          ((__bf16*)Cp)[row * N + col] = f2bf(acc[mi][ni][i]);
        else
          ((float*)Cp)[row * N + col] = acc[mi][ni][i];
      }
}

// ---------------- causal flash attention ----------------
// grid (64, 16): 64 q-blocks of 64 rows, 16 heads. 256 threads = 4 waves,
// each wave owns 16 q rows. KV tiles of 64 keys.
__global__ __launch_bounds__(256) void attn_fwd(const __bf16* __restrict__ Q,
                                                const __bf16* __restrict__ Kg,
                                                const __bf16* __restrict__ Vg,
                                                __bf16* __restrict__ O) {
  const int qb = (int)gridDim.x - 1 - (int)blockIdx.x;  // longest blocks dispatch first
  const int h = blockIdx.y;
  __shared__ __bf16 Ks[64 * 64];      // [key][d]
  __shared__ __bf16 Vts[64 * 64];     // [d][key] (transposed)
  __shared__ __bf16 Ps[4][16 * 64];   // per-wave P tile [qrow][key]

  const int tid = threadIdx.x;
  const int lane = tid & 63;
  const int wave = tid >> 6;
  const int c16 = lane & 15, g4 = lane >> 4;
  const int qrow0 = qb * 64 + wave * 16;

  // Q fragments: row = c16, d = dh*32 + g4*8 + j
  bf16x8 qa[2];
  {
    const __bf16* qp = Q + (size_t)(qrow0 + c16) * C_DIM + h * D_HEAD + g4 * 8;
    qa[0] = *(const bf16x8*)qp;
    qa[1] = *(const bf16x8*)(qp + 32);
  }

  f32x4 acc[4] = {};
  float mrow[4], lrow[4];
#pragma unroll
  for (int i = 0; i < 4; ++i) { mrow[i] = -1e30f; lrow[i] = 0.f; }

  const int ntiles = qb + 1;
  for (int t = 0; t < ntiles; ++t) {
    const int kv0 = t * 64;
    // stage K tile via global_load_lds (linear [key][d])
#pragma unroll
    for (int i = 0; i < 2; ++i) {
      const int key = (i * 4 + wave) * 8 + (lane >> 3);
      const int d0 = (lane & 7) * 8;
      gload_lds16(Kg + (size_t)(kv0 + key) * C_DIM + h * D_HEAD + d0,
                  Ks + (i * 4 + wave) * 512);
    }
    // stage V transposed (manual): Vts[d][key]
#pragma unroll
    for (int i = 0; i < 2; ++i) {
      const int key = i * 32 + (tid >> 3);
      const int d0 = (tid & 7) * 8;
      bf16x8 v = *(const bf16x8*)(Vg + (size_t)(kv0 + key) * C_DIM + h * D_HEAD + d0);
#pragma unroll
      for (int j = 0; j < 8; ++j) Vts[(d0 + j) * 64 + key] = v[j];
    }
    __syncthreads();

    // S = Q K^T  (rows = q, cols = key), 4 col-groups of 16
    f32x4 s[4];
#pragma unroll
    for (int n = 0; n < 4; ++n) {
      const __bf16* kp = Ks + (n * 16 + c16) * 64 + g4 * 8;
      bf16x8 k0 = *(const bf16x8*)kp;
      bf16x8 k1 = *(const bf16x8*)(kp + 32);
      f32x4 z = {};
      z = __builtin_amdgcn_mfma_f32_16x16x32_bf16(qa[0], k0, z, 0, 0, 0);
      z = __builtin_amdgcn_mfma_f32_16x16x32_bf16(qa[1], k1, z, 0, 0, 0);
      s[n] = z;
    }
    // scale + causal mask
#pragma unroll
    for (int n = 0; n < 4; ++n) {
      const int key = kv0 + n * 16 + c16;
#pragma unroll
      for (int i = 0; i < 4; ++i) {
        const int q = qrow0 + g4 * 4 + i;
        float v = s[n][i] * 0.125f;
        s[n][i] = (key <= q) ? v : -1e30f;
      }
    }
    // online softmax (rows live on 16-lane groups; reduce over lane&15)
    float corr[4];
#pragma unroll
    for (int i = 0; i < 4; ++i) {
      float v = fmaxf(fmaxf(s[0][i], s[1][i]), fmaxf(s[2][i], s[3][i]));
      v = fmaxf(v, __shfl_xor(v, 1, 64));
      v = fmaxf(v, __shfl_xor(v, 2, 64));
      v = fmaxf(v, __shfl_xor(v, 4, 64));
      v = fmaxf(v, __shfl_xor(v, 8, 64));
      const float mnew = fmaxf(mrow[i], v);
      corr[i] = __expf(mrow[i] - mnew);
      mrow[i] = mnew;
    }
    float rs[4] = {0.f, 0.f, 0.f, 0.f};
#pragma unroll
    for (int n = 0; n < 4; ++n)
#pragma unroll
      for (int i = 0; i < 4; ++i) {
        const float p = __expf(s[n][i] - mrow[i]);
        s[n][i] = p;
        rs[i] += p;
      }
#pragma unroll
    for (int i = 0; i < 4; ++i) {
      float v = rs[i];
      v += __shfl_xor(v, 1, 64);
      v += __shfl_xor(v, 2, 64);
      v += __shfl_xor(v, 4, 64);
      v += __shfl_xor(v, 8, 64);
      lrow[i] = lrow[i] * corr[i] + v;
    }
#pragma unroll
    for (int n = 0; n < 4; ++n)
#pragma unroll
      for (int i = 0; i < 4; ++i) acc[n][i] *= corr[i];

    // P -> LDS (per-wave buffer), then PV
    __bf16* pw = &Ps[wave][0];
#pragma unroll
    for (int n = 0; n < 4; ++n)
#pragma unroll
      for (int i = 0; i < 4; ++i)
        pw[(g4 * 4 + i) * 64 + n * 16 + c16] = f2bf(s[n][i]);
    asm volatile("s_waitcnt lgkmcnt(0)" ::: "memory");
    __builtin_amdgcn_sched_barrier(0);

#pragma unroll
    for (int kh = 0; kh < 2; ++kh) {
      bf16x8 pa = *(const bf16x8*)(pw + c16 * 64 + kh * 32 + g4 * 8);
#pragma unroll
      for (int n = 0; n < 4; ++n) {
        bf16x8 vb = *(const bf16x8*)(Vts + (n * 16 + c16) * 64 + kh * 32 + g4 * 8);
        acc[n] = __builtin_amdgcn_mfma_f32_16x16x32_bf16(pa, vb, acc[n], 0, 0, 0);
      }
    }
    __syncthreads();
  }

  // epilogue: normalize and store
#pragma unroll
  for (int n = 0; n < 4; ++n)
#pragma unroll
    for (int i = 0; i < 4; ++i) {
      const int q = qrow0 + g4 * 4 + i;
      O[(size_t)q * C_DIM + h * D_HEAD + n * 16 + c16] = f2bf(acc[n][i] / lrow[i]);
    }
}

extern "C" void kernel_launch(void* const* d_in, const int* in_sizes, int n_in,
                              void* d_out, int out_size, void* d_ws, size_t ws_size,
                              hipStream_t stream) {
  const float* x = (const float*)d_in[0];
  const float* Wq = (const float*)d_in[1];
  const float* Wk = (const float*)d_in[2];
  const float* Wv = (const float*)d_in[3];
  const float* Wo = (const float*)d_in[4];
  float* out = (float*)d_out;

  char* ws = (char*)d_ws;
  __bf16* xb  = (__bf16*)(ws);                       // 8 MiB
  __bf16* WqT = (__bf16*)(ws + (8u << 20));          // 2 MiB each
  __bf16* WkT = (__bf16*)(ws + (10u << 20));
  __bf16* WvT = (__bf16*)(ws + (12u << 20));
  __bf16* WoT = (__bf16*)(ws + (14u << 20));
  __bf16* Qb  = (__bf16*)(ws + (16u << 20));         // 8 MiB each
  __bf16* Kb  = (__bf16*)(ws + (24u << 20));
  __bf16* Vb  = (__bf16*)(ws + (32u << 20));
  __bf16* Ab  = (__bf16*)(ws + (40u << 20));         // attention out, 8 MiB

  // x -> bf16 (4M elems, 4/thread)
  cvt_f32_bf16<<<4096, 256, 0, stream>>>(x, xb);

  dim3 tb(32, 8);
  dim3 tg(32, 32);
  transpose_cvt<<<tg, tb, 0, stream>>>(Wq, WqT);
  transpose_cvt<<<tg, tb, 0, stream>>>(Wk, WkT);
  transpose_cvt<<<tg, tb, 0, stream>>>(Wv, WvT);
  transpose_cvt<<<tg, tb, 0, stream>>>(Wo, WoT);

  dim3 gg(L_SEQ / 128, C_DIM / 128);  // (32, 8)
  gemm_bt<true><<<gg, 256, 0, stream>>>(xb, WqT, Qb, L_SEQ, C_DIM, C_DIM);
  gemm_bt<true><<<gg, 256, 0, stream>>>(xb, WkT, Kb, L_SEQ, C_DIM, C_DIM);
  gemm_bt<true><<<gg, 256, 0, stream>>>(xb, WvT, Vb, L_SEQ, C_DIM, C_DIM);

  attn_fwd<<<dim3(L_SEQ / 64, H_NUM), 256, 0, stream>>>(Qb, Kb, Vb, Ab);

  gemm_bt<false><<<gg, 256, 0, stream>>>(Ab, WoT, out, L_SEQ, C_DIM, C_DIM);
}

// Round 2
// 423.980 us; speedup vs baseline: 1.3604x; 1.3604x over previous
//
#include <hip/hip_runtime.h>

// Problem constants (B=1)
#define L_SEQ 4096
#define C_DIM 1024
#define H_NUM 16
#define D_HEAD 64
#define LDQKV 3072

typedef __bf16 bf16x8 __attribute__((ext_vector_type(8)));
typedef __bf16 bf16x4 __attribute__((ext_vector_type(4)));
typedef float f32x4 __attribute__((ext_vector_type(4)));

#define AS1 __attribute__((address_space(1)))
#define AS3 __attribute__((address_space(3)))

__device__ inline __bf16 f2bf(float f) {
  unsigned u = __builtin_bit_cast(unsigned, f);
  u = (u + 0x7fffu + ((u >> 16) & 1u)) >> 16;
  unsigned short s = (unsigned short)u;
  return __builtin_bit_cast(__bf16, s);
}

__device__ inline void gload_lds16(const __bf16* g, __bf16* l) {
  __builtin_amdgcn_global_load_lds((const AS1 void*)g, (AS3 void*)l, 16, 0, 0);
}

// ---------------- x fp32 -> bf16 ----------------
__global__ __launch_bounds__(256) void cvt_f32_bf16(const float* __restrict__ in,
                                                    __bf16* __restrict__ out) {
  int i = (blockIdx.x * 256 + threadIdx.x) * 4;
  float4 v = *(const float4*)(in + i);
  bf16x4 o = {f2bf(v.x), f2bf(v.y), f2bf(v.z), f2bf(v.w)};
  *(bf16x4*)(out + i) = o;
}

// ---------------- W (K x N) fp32 -> Wt (N x K) bf16 ----------------
__global__ __launch_bounds__(256) void transpose_cvt(const float* __restrict__ W,
                                                     __bf16* __restrict__ Wt) {
  __shared__ float t[32][33];
  const int tx = threadIdx.x, ty = threadIdx.y;
  const int c0 = blockIdx.x * 32, r0 = blockIdx.y * 32;
#pragma unroll
  for (int k = 0; k < 4; ++k)
    t[ty + k * 8][tx] = W[(size_t)(r0 + ty + k * 8) * C_DIM + c0 + tx];
  __syncthreads();
#pragma unroll
  for (int k = 0; k < 4; ++k)
    Wt[(size_t)(c0 + ty + k * 8) * C_DIM + r0 + tx] = f2bf(t[tx][ty + k * 8]);
}

// ---------------- V slice of QKV -> Vt [C][L] bf16 ----------------
__global__ __launch_bounds__(256) void transpose_v(const __bf16* __restrict__ QKV,
                                                   __bf16* __restrict__ Vt) {
  __shared__ __bf16 t[32][34];
  const int tx = threadIdx.x, ty = threadIdx.y;
  const int q0 = blockIdx.x * 32, c0 = blockIdx.y * 32;
#pragma unroll
  for (int k = 0; k < 4; ++k)
    t[ty + k * 8][tx] = QKV[(size_t)(q0 + ty + k * 8) * LDQKV + 2048 + c0 + tx];
  __syncthreads();
#pragma unroll
  for (int k = 0; k < 4; ++k)
    Vt[(size_t)(c0 + ty + k * 8) * L_SEQ + q0 + tx] = t[tx][ty + k * 8];
}

// ---------------- GEMM: C(MxN) = A(MxK,bf16) * Bt(NxK,bf16)^T ----------------
template <bool OUT_BF16>
__global__ __launch_bounds__(256) void gemm_bt(const __bf16* __restrict__ A,
                                               const __bf16* __restrict__ Bt,
                                               void* __restrict__ Cp,
                                               int M, int N, int K) {
  __shared__ __bf16 As[128 * 32];
  __shared__ __bf16 Bs[128 * 32];
  const int tid = threadIdx.x;
  const int lane = tid & 63;
  const int wave = tid >> 6;
  const int wm = wave >> 1, wn = wave & 1;
  const int c16 = lane & 15, g4 = lane >> 4;
  const int srow = lane >> 2, scol = (lane & 3) * 8;

  f32x4 acc[4][4] = {};

  const size_t arow0 = (size_t)blockIdx.x * 128;
  const size_t brow0 = (size_t)blockIdx.y * 128;

  for (int kt = 0; kt < K; kt += 32) {
#pragma unroll
    for (int i = 0; i < 2; ++i) {
      const int row = i * 64 + wave * 16 + srow;
      gload_lds16(A + (arow0 + row) * K + kt + scol, As + (i * 64 + wave * 16) * 32);
      gload_lds16(Bt + (brow0 + row) * K + kt + scol, Bs + (i * 64 + wave * 16) * 32);
    }
    __syncthreads();
    bf16x8 af[4], bfr[4];
#pragma unroll
    for (int mi = 0; mi < 4; ++mi)
      af[mi] = *(const bf16x8*)(As + (wm * 64 + mi * 16 + c16) * 32 + g4 * 8);
#pragma unroll
    for (int ni = 0; ni < 4; ++ni)
      bfr[ni] = *(const bf16x8*)(Bs + (wn * 64 + ni * 16 + c16) * 32 + g4 * 8);
#pragma unroll
    for (int mi = 0; mi < 4; ++mi)
#pragma unroll
      for (int ni = 0; ni < 4; ++ni)
        acc[mi][ni] = __builtin_amdgcn_mfma_f32_16x16x32_bf16(af[mi], bfr[ni], acc[mi][ni], 0, 0, 0);
    __syncthreads();
  }

#pragma unroll
  for (int mi = 0; mi < 4; ++mi)
#pragma unroll
    for (int ni = 0; ni < 4; ++ni)
#pragma unroll
      for (int i = 0; i < 4; ++i) {
        size_t row = arow0 + wm * 64 + mi * 16 + g4 * 4 + i;
        size_t col = brow0 + wn * 64 + ni * 16 + c16;
        if (OUT_BF16)
          ((__bf16*)Cp)[row * N + col] = f2bf(acc[mi][ni][i]);
        else
          ((float*)Cp)[row * N + col] = acc[mi][ni][i];
      }
}

// ---------------- causal flash attention ----------------
// grid (64, 16): 64 q-blocks of 64 rows, 16 heads. 256 threads = 4 waves,
// each wave owns 16 q rows. KV tiles of 64 keys. All LDS XOR-swizzled (T2).
__global__ __launch_bounds__(256) void attn_fwd(const __bf16* __restrict__ Q,
                                                const __bf16* __restrict__ Kg,
                                                const __bf16* __restrict__ Vt,
                                                __bf16* __restrict__ O) {
  const int qb = (int)gridDim.x - 1 - (int)blockIdx.x;  // longest blocks first
  const int h = blockIdx.y;
  __shared__ __bf16 Ks[64 * 64];   // [key][d], rows XOR-swizzled in 16B chunks
  __shared__ __bf16 Vs[64 * 64];   // [d][key], rows XOR-swizzled
  __shared__ __bf16 Ps[4][16 * 64];// per-wave P [q][key], rows XOR-swizzled
  char* const KsB = (char*)Ks;
  char* const VsB = (char*)Vs;

  const int tid = threadIdx.x;
  const int lane = tid & 63;
  const int wave = tid >> 6;
  const int c16 = lane & 15, g4 = lane >> 4;
  const int qrow0 = qb * 64 + wave * 16;
  constexpr float SC = 0.125f * 1.44269504088896f;  // scale * log2(e)

  // Q fragments: row = c16, d = kh*32 + g4*8 + j
  bf16x8 qa[2];
  {
    const __bf16* qp = Q + (size_t)(qrow0 + c16) * LDQKV + h * D_HEAD + g4 * 8;
    qa[0] = *(const bf16x8*)qp;
    qa[1] = *(const bf16x8*)(qp + 32);
  }

  f32x4 acc[4] = {};
  float mrow[4], lrow[4];
#pragma unroll
  for (int i = 0; i < 4; ++i) { mrow[i] = -1e30f; lrow[i] = 0.f; }

  // staging: linear LDS dest; source chunk pre-permuted so effective layout
  // is byte-swizzled (chunk ^= row&7)
  const int rl = lane >> 3;              // row within 8-row group
  const int cs = (lane & 7) ^ (rl & 7);  // swizzled source 16B-chunk

  const int nt = qb + 1;
  for (int t = 0; t < nt; ++t) {
    const int kv0 = t * 64;
#pragma unroll
    for (int i = 0; i < 2; ++i) {
      const int r = (i * 4 + wave) * 8 + rl;
      gload_lds16(Kg + (size_t)(kv0 + r) * LDQKV + h * D_HEAD + cs * 8,
                  Ks + (i * 4 + wave) * 512);
      gload_lds16(Vt + (size_t)(h * D_HEAD + r) * L_SEQ + kv0 + cs * 8,
                  Vs + (i * 4 + wave) * 512);
    }
    __syncthreads();

    // S = Q K^T
    f32x4 s[4];
#pragma unroll
    for (int n = 0; n < 4; ++n) {
      const int row = n * 16 + c16;
      const int rb = row * 128;
      const int x7 = row & 7;
      bf16x8 k0 = *(const bf16x8*)(KsB + rb + ((g4 ^ x7) << 4));
      bf16x8 k1 = *(const bf16x8*)(KsB + rb + (((4 + g4) ^ x7) << 4));
      f32x4 z = {};
      z = __builtin_amdgcn_mfma_f32_16x16x32_bf16(qa[0], k0, z, 0, 0, 0);
      z = __builtin_amdgcn_mfma_f32_16x16x32_bf16(qa[1], k1, z, 0, 0, 0);
      s[n] = z;
    }
    if (t == qb) {  // diagonal tile: causal mask
#pragma unroll
      for (int n = 0; n < 4; ++n) {
        const int key = kv0 + n * 16 + c16;
#pragma unroll
        for (int i = 0; i < 4; ++i) {
          const int q = qrow0 + g4 * 4 + i;
          s[n][i] = (key <= q) ? s[n][i] * SC : -1e30f;
        }
      }
    } else {
#pragma unroll
      for (int n = 0; n < 4; ++n)
#pragma unroll
        for (int i = 0; i < 4; ++i) s[n][i] *= SC;
    }

    // online softmax (rows on 16-lane groups)
    float corr[4];
#pragma unroll
    for (int i = 0; i < 4; ++i) {
      float v = fmaxf(fmaxf(s[0][i], s[1][i]), fmaxf(s[2][i], s[3][i]));
      v = fmaxf(v, __shfl_xor(v, 1, 64));
      v = fmaxf(v, __shfl_xor(v, 2, 64));
      v = fmaxf(v, __shfl_xor(v, 4, 64));
      v = fmaxf(v, __shfl_xor(v, 8, 64));
      const float mnew = fmaxf(mrow[i], v);
      corr[i] = exp2f(mrow[i] - mnew);
      mrow[i] = mnew;
    }
    float rs[4] = {0.f, 0.f, 0.f, 0.f};
#pragma unroll
    for (int n = 0; n < 4; ++n)
#pragma unroll
      for (int i = 0; i < 4; ++i) {
        const float p = exp2f(s[n][i] - mrow[i]);
        s[n][i] = p;
        rs[i] += p;
      }
#pragma unroll
    for (int i = 0; i < 4; ++i) {
      float v = rs[i];
      v += __shfl_xor(v, 1, 64);
      v += __shfl_xor(v, 2, 64);
      v += __shfl_xor(v, 4, 64);
      v += __shfl_xor(v, 8, 64);
      lrow[i] = lrow[i] * corr[i] + v;
    }
#pragma unroll
    for (int n = 0; n < 4; ++n)
#pragma unroll
      for (int i = 0; i < 4; ++i) acc[n][i] *= corr[i];

    // P -> per-wave LDS (swizzled), then PV
    char* const pw = (char*)&Ps[wave][0];
#pragma unroll
    for (int n = 0; n < 4; ++n) {
      const int ch = n * 2 + (c16 >> 3);
#pragma unroll
      for (int i = 0; i < 4; ++i) {
        const int row = g4 * 4 + i;
        *(__bf16*)(pw + row * 128 + ((ch ^ (row & 7)) << 4) + (c16 & 7) * 2) =
            f2bf(s[n][i]);
      }
    }
    asm volatile("s_waitcnt lgkmcnt(0)" ::: "memory");
    __builtin_amdgcn_sched_barrier(0);

#pragma unroll
    for (int kh = 0; kh < 2; ++kh) {
      const int chk = kh * 4 + g4;
      bf16x8 pa = *(const bf16x8*)(pw + c16 * 128 + ((chk ^ (c16 & 7)) << 4));
#pragma unroll
      for (int n = 0; n < 4; ++n) {
        const int row = n * 16 + c16;
        bf16x8 vb = *(const bf16x8*)(VsB + row * 128 + ((chk ^ (row & 7)) << 4));
        acc[n] = __builtin_amdgcn_mfma_f32_16x16x32_bf16(pa, vb, acc[n], 0, 0, 0);
      }
    }
    __syncthreads();
  }

  // epilogue: normalize and store
#pragma unroll
  for (int n = 0; n < 4; ++n)
#pragma unroll
    for (int i = 0; i < 4; ++i) {
      const int q = qrow0 + g4 * 4 + i;
      O[(size_t)q * C_DIM + h * D_HEAD + n * 16 + c16] = f2bf(acc[n][i] / lrow[i]);
    }
}

extern "C" void kernel_launch(void* const* d_in, const int* in_sizes, int n_in,
                              void* d_out, int out_size, void* d_ws, size_t ws_size,
                              hipStream_t stream) {
  const float* x = (const float*)d_in[0];
  const float* Wq = (const float*)d_in[1];
  const float* Wk = (const float*)d_in[2];
  const float* Wv = (const float*)d_in[3];
  const float* Wo = (const float*)d_in[4];
  float* out = (float*)d_out;

  char* ws = (char*)d_ws;
  __bf16* xb    = (__bf16*)(ws);                 // [0,8M)  x bf16; later reused as Ab
  __bf16* WqkvT = (__bf16*)(ws + (8u << 20));    // [8M,14M)  3x 1024x1024 bf16
  __bf16* WoT   = (__bf16*)(ws + (14u << 20));   // [14M,16M)
  __bf16* QKVb  = (__bf16*)(ws + (16u << 20));   // [16M,40M)  4096x3072 bf16
  __bf16* Vtb   = (__bf16*)(ws + (40u << 20));   // [40M,48M)  1024x4096 bf16
  __bf16* Ab    = xb;                            // attention out aliases xb (dead by then)

  cvt_f32_bf16<<<4096, 256, 0, stream>>>(x, xb);

  dim3 tb(32, 8);
  dim3 tg(32, 32);
  transpose_cvt<<<tg, tb, 0, stream>>>(Wq, WqkvT);
  transpose_cvt<<<tg, tb, 0, stream>>>(Wk, WqkvT + (size_t)1024 * 1024);
  transpose_cvt<<<tg, tb, 0, stream>>>(Wv, WqkvT + (size_t)2048 * 1024);
  transpose_cvt<<<tg, tb, 0, stream>>>(Wo, WoT);

  // fused QKV projection: [4096,1024] x [1024,3072] -> [4096,3072]
  gemm_bt<true><<<dim3(L_SEQ / 128, LDQKV / 128), 256, 0, stream>>>(
      xb, WqkvT, QKVb, L_SEQ, LDQKV, C_DIM);

  // V slice -> Vt [1024][4096]
  transpose_v<<<dim3(L_SEQ / 32, C_DIM / 32), tb, 0, stream>>>(QKVb, Vtb);

  attn_fwd<<<dim3(L_SEQ / 64, H_NUM), 256, 0, stream>>>(
      QKVb, QKVb + 1024, Vtb, Ab);

  gemm_bt<false><<<dim3(L_SEQ / 128, C_DIM / 128), 256, 0, stream>>>(
      Ab, WoT, out, L_SEQ, C_DIM, C_DIM);
}

// Round 3
// 287.888 us; speedup vs baseline: 2.0035x; 1.4727x over previous
//
#include <hip/hip_runtime.h>

// Problem constants (B=1)
#define L_SEQ 4096
#define C_DIM 1024
#define H_NUM 16
#define D_HEAD 64
#define LDQKV 3072

typedef __bf16 bf16x8 __attribute__((ext_vector_type(8)));
typedef __bf16 bf16x4 __attribute__((ext_vector_type(4)));
typedef float f32x4 __attribute__((ext_vector_type(4)));

#define AS1 __attribute__((address_space(1)))
#define AS3 __attribute__((address_space(3)))

__device__ inline __bf16 f2bf(float f) {
  unsigned u = __builtin_bit_cast(unsigned, f);
  u = (u + 0x7fffu + ((u >> 16) & 1u)) >> 16;
  unsigned short s = (unsigned short)u;
  return __builtin_bit_cast(__bf16, s);
}

__device__ inline void gload_lds16(const __bf16* g, __bf16* l) {
  __builtin_amdgcn_global_load_lds((const AS1 void*)g, (AS3 void*)l, 16, 0, 0);
}

// ---------------- x fp32 -> bf16 ----------------
__global__ __launch_bounds__(256) void cvt_f32_bf16(const float* __restrict__ in,
                                                    __bf16* __restrict__ out) {
  int i = (blockIdx.x * 256 + threadIdx.x) * 4;
  float4 v = *(const float4*)(in + i);
  bf16x4 o = {f2bf(v.x), f2bf(v.y), f2bf(v.z), f2bf(v.w)};
  *(bf16x4*)(out + i) = o;
}

// ---------------- W (K x N) fp32 -> Wt (N x K) bf16 ----------------
__global__ __launch_bounds__(256) void transpose_cvt(const float* __restrict__ W,
                                                     __bf16* __restrict__ Wt) {
  __shared__ float t[32][33];
  const int tx = threadIdx.x, ty = threadIdx.y;
  const int c0 = blockIdx.x * 32, r0 = blockIdx.y * 32;
#pragma unroll
  for (int k = 0; k < 4; ++k)
    t[ty + k * 8][tx] = W[(size_t)(r0 + ty + k * 8) * C_DIM + c0 + tx];
  __syncthreads();
#pragma unroll
  for (int k = 0; k < 4; ++k)
    Wt[(size_t)(c0 + ty + k * 8) * C_DIM + r0 + tx] = f2bf(t[tx][ty + k * 8]);
}

// ---------------- V slice of QKV -> Vt [C][L] bf16 ----------------
__global__ __launch_bounds__(256) void transpose_v(const __bf16* __restrict__ QKV,
                                                   __bf16* __restrict__ Vt) {
  __shared__ __bf16 t[32][34];
  const int tx = threadIdx.x, ty = threadIdx.y;
  const int q0 = blockIdx.x * 32, c0 = blockIdx.y * 32;
#pragma unroll
  for (int k = 0; k < 4; ++k)
    t[ty + k * 8][tx] = QKV[(size_t)(q0 + ty + k * 8) * LDQKV + 2048 + c0 + tx];
  __syncthreads();
#pragma unroll
  for (int k = 0; k < 4; ++k)
    Vt[(size_t)(c0 + ty + k * 8) * L_SEQ + q0 + tx] = t[tx][ty + k * 8];
}

// ---------------- GEMM: C(MxN) = A(MxK,bf16) * Bt(NxK,bf16)^T ----------------
template <bool OUT_BF16>
__global__ __launch_bounds__(256) void gemm_bt(const __bf16* __restrict__ A,
                                               const __bf16* __restrict__ Bt,
                                               void* __restrict__ Cp,
                                               int M, int N, int K) {
  __shared__ __bf16 As[128 * 32];
  __shared__ __bf16 Bs[128 * 32];
  const int tid = threadIdx.x;
  const int lane = tid & 63;
  const int wave = tid >> 6;
  const int wm = wave >> 1, wn = wave & 1;
  const int c16 = lane & 15, g4 = lane >> 4;
  const int srow = lane >> 2, scol = (lane & 3) * 8;

  f32x4 acc[4][4] = {};

  const size_t arow0 = (size_t)blockIdx.x * 128;
  const size_t brow0 = (size_t)blockIdx.y * 128;

  for (int kt = 0; kt < K; kt += 32) {
#pragma unroll
    for (int i = 0; i < 2; ++i) {
      const int row = i * 64 + wave * 16 + srow;
      gload_lds16(A + (arow0 + row) * K + kt + scol, As + (i * 64 + wave * 16) * 32);
      gload_lds16(Bt + (brow0 + row) * K + kt + scol, Bs + (i * 64 + wave * 16) * 32);
    }
    __syncthreads();
    bf16x8 af[4], bfr[4];
#pragma unroll
    for (int mi = 0; mi < 4; ++mi)
      af[mi] = *(const bf16x8*)(As + (wm * 64 + mi * 16 + c16) * 32 + g4 * 8);
#pragma unroll
    for (int ni = 0; ni < 4; ++ni)
      bfr[ni] = *(const bf16x8*)(Bs + (wn * 64 + ni * 16 + c16) * 32 + g4 * 8);
#pragma unroll
    for (int mi = 0; mi < 4; ++mi)
#pragma unroll
      for (int ni = 0; ni < 4; ++ni)
        acc[mi][ni] = __builtin_amdgcn_mfma_f32_16x16x32_bf16(af[mi], bfr[ni], acc[mi][ni], 0, 0, 0);
    __syncthreads();
  }

#pragma unroll
  for (int mi = 0; mi < 4; ++mi)
#pragma unroll
    for (int ni = 0; ni < 4; ++ni)
#pragma unroll
      for (int i = 0; i < 4; ++i) {
        size_t row = arow0 + wm * 64 + mi * 16 + g4 * 4 + i;
        size_t col = brow0 + wn * 64 + ni * 16 + c16;
        if (OUT_BF16)
          ((__bf16*)Cp)[row * N + col] = f2bf(acc[mi][ni][i]);
        else
          ((float*)Cp)[row * N + col] = acc[mi][ni][i];
      }
}

// ---------------- causal flash attention (paired + double-buffered) ----------
// grid 512: 32 complementary q-tile pairs x 16 heads. Block p handles q-tiles
// {63-p, p} => exactly 65 KV tiles per block. 4 waves x 16 q rows. K/V tiles
// double-buffered with counted vmcnt; all LDS XOR-swizzled.
__global__ __launch_bounds__(256) void attn_fwd(const __bf16* __restrict__ Q,
                                                const __bf16* __restrict__ Kg,
                                                const __bf16* __restrict__ Vt,
                                                __bf16* __restrict__ O) {
  const int bid = blockIdx.x;
  const int h = bid & 15;
  const int p = bid >> 4;
  const int qt0 = 63 - p, qt1 = p;

  __shared__ __bf16 Ks[2][64 * 64];
  __shared__ __bf16 Vs[2][64 * 64];
  __shared__ __bf16 Ps[4][16 * 64];

  const int tid = threadIdx.x;
  const int lane = tid & 63;
  const int wave = tid >> 6;
  const int c16 = lane & 15, g4 = lane >> 4;
  constexpr float SC = 0.125f * 1.44269504088896f;

  const int rl = lane >> 3;
  const int cs = (lane & 7) ^ rl;

  // stage K/V tile kv into buffer b (4 gload_lds per thread)
  auto stage = [&](int kv, int b) {
#pragma unroll
    for (int i = 0; i < 2; ++i) {
      const int r = (i * 4 + wave) * 8 + rl;
      gload_lds16(Kg + (size_t)(kv * 64 + r) * LDQKV + h * D_HEAD + cs * 8,
                  &Ks[b][(i * 4 + wave) * 512]);
      gload_lds16(Vt + (size_t)(h * D_HEAD + r) * L_SEQ + kv * 64 + cs * 8,
                  &Vs[b][(i * 4 + wave) * 512]);
    }
  };

  int cur = 0;
  stage(0, 0);

#pragma unroll
  for (int seg = 0; seg < 2; ++seg) {
    const int qtc = seg ? qt1 : qt0;
    const int qrow0 = qtc * 64 + wave * 16;

    // Q fragments for this segment
    const __bf16* qp = Q + (size_t)(qrow0 + c16) * LDQKV + h * D_HEAD + g4 * 8;
    bf16x8 qa0 = *(const bf16x8*)qp;
    bf16x8 qa1 = *(const bf16x8*)(qp + 32);

    f32x4 acc[4] = {};
    float mrow[4], lrow[4];
#pragma unroll
    for (int i = 0; i < 4; ++i) { mrow[i] = -1e30f; lrow[i] = 0.f; }

    for (int kv = 0; kv <= qtc; ++kv) {
      // prefetch next tile (within segment, or segment 1's tile 0)
      const bool have_next = (kv < qtc) || (seg == 0);
      if (have_next) {
        stage((kv < qtc) ? kv + 1 : 0, cur ^ 1);
        asm volatile("s_waitcnt vmcnt(4)" ::: "memory");
      } else {
        asm volatile("s_waitcnt vmcnt(0)" ::: "memory");
      }
      __builtin_amdgcn_sched_barrier(0);
      __builtin_amdgcn_s_barrier();
      __builtin_amdgcn_sched_barrier(0);

      char* const KsB = (char*)&Ks[cur][0];
      char* const VsB = (char*)&Vs[cur][0];
      const int kv0 = kv * 64;

      // S = Q K^T
      f32x4 s[4];
      __builtin_amdgcn_s_setprio(1);
#pragma unroll
      for (int n = 0; n < 4; ++n) {
        const int row = n * 16 + c16;
        const int rb = row * 128;
        const int x7 = row & 7;
        bf16x8 k0 = *(const bf16x8*)(KsB + rb + ((g4 ^ x7) << 4));
        bf16x8 k1 = *(const bf16x8*)(KsB + rb + (((4 + g4) ^ x7) << 4));
        f32x4 z = {};
        z = __builtin_amdgcn_mfma_f32_16x16x32_bf16(qa0, k0, z, 0, 0, 0);
        z = __builtin_amdgcn_mfma_f32_16x16x32_bf16(qa1, k1, z, 0, 0, 0);
        s[n] = z;
      }
      __builtin_amdgcn_s_setprio(0);

      if (kv == qtc) {  // diagonal tile
#pragma unroll
        for (int n = 0; n < 4; ++n) {
          const int key = kv0 + n * 16 + c16;
#pragma unroll
          for (int i = 0; i < 4; ++i) {
            const int q = qrow0 + g4 * 4 + i;
            s[n][i] = (key <= q) ? s[n][i] * SC : -1e30f;
          }
        }
      } else {
#pragma unroll
        for (int n = 0; n < 4; ++n)
#pragma unroll
          for (int i = 0; i < 4; ++i) s[n][i] *= SC;
      }

      // online softmax
      float corr[4];
#pragma unroll
      for (int i = 0; i < 4; ++i) {
        float v = fmaxf(fmaxf(s[0][i], s[1][i]), fmaxf(s[2][i], s[3][i]));
        v = fmaxf(v, __shfl_xor(v, 1, 64));
        v = fmaxf(v, __shfl_xor(v, 2, 64));
        v = fmaxf(v, __shfl_xor(v, 4, 64));
        v = fmaxf(v, __shfl_xor(v, 8, 64));
        const float mnew = fmaxf(mrow[i], v);
        corr[i] = exp2f(mrow[i] - mnew);
        mrow[i] = mnew;
      }
      float rs[4] = {0.f, 0.f, 0.f, 0.f};
#pragma unroll
      for (int n = 0; n < 4; ++n)
#pragma unroll
        for (int i = 0; i < 4; ++i) {
          const float pv = exp2f(s[n][i] - mrow[i]);
          s[n][i] = pv;
          rs[i] += pv;
        }
#pragma unroll
      for (int i = 0; i < 4; ++i) {
        float v = rs[i];
        v += __shfl_xor(v, 1, 64);
        v += __shfl_xor(v, 2, 64);
        v += __shfl_xor(v, 4, 64);
        v += __shfl_xor(v, 8, 64);
        lrow[i] = lrow[i] * corr[i] + v;
      }
#pragma unroll
      for (int n = 0; n < 4; ++n)
#pragma unroll
        for (int i = 0; i < 4; ++i) acc[n][i] *= corr[i];

      // P -> per-wave LDS (swizzled), then PV
      char* const pw = (char*)&Ps[wave][0];
#pragma unroll
      for (int n = 0; n < 4; ++n) {
        const int ch = n * 2 + (c16 >> 3);
#pragma unroll
        for (int i = 0; i < 4; ++i) {
          const int row = g4 * 4 + i;
          *(__bf16*)(pw + row * 128 + ((ch ^ (row & 7)) << 4) + (c16 & 7) * 2) =
              f2bf(s[n][i]);
        }
      }
      asm volatile("s_waitcnt lgkmcnt(0)" ::: "memory");
      __builtin_amdgcn_sched_barrier(0);

      __builtin_amdgcn_s_setprio(1);
#pragma unroll
      for (int kh = 0; kh < 2; ++kh) {
        const int chk = kh * 4 + g4;
        bf16x8 pa = *(const bf16x8*)(pw + c16 * 128 + ((chk ^ (c16 & 7)) << 4));
#pragma unroll
        for (int n = 0; n < 4; ++n) {
          const int row = n * 16 + c16;
          bf16x8 vb = *(const bf16x8*)(VsB + row * 128 + ((chk ^ (row & 7)) << 4));
          acc[n] = __builtin_amdgcn_mfma_f32_16x16x32_bf16(pa, vb, acc[n], 0, 0, 0);
        }
      }
      __builtin_amdgcn_s_setprio(0);

      __builtin_amdgcn_sched_barrier(0);
      __builtin_amdgcn_s_barrier();
      __builtin_amdgcn_sched_barrier(0);
      cur ^= 1;
    }

    // segment epilogue: normalize and store
#pragma unroll
    for (int n = 0; n < 4; ++n)
#pragma unroll
      for (int i = 0; i < 4; ++i) {
        const int q = qrow0 + g4 * 4 + i;
        O[(size_t)q * C_DIM + h * D_HEAD + n * 16 + c16] = f2bf(acc[n][i] / lrow[i]);
      }
  }
}

extern "C" void kernel_launch(void* const* d_in, const int* in_sizes, int n_in,
                              void* d_out, int out_size, void* d_ws, size_t ws_size,
                              hipStream_t stream) {
  const float* x = (const float*)d_in[0];
  const float* Wq = (const float*)d_in[1];
  const float* Wk = (const float*)d_in[2];
  const float* Wv = (const float*)d_in[3];
  const float* Wo = (const float*)d_in[4];
  float* out = (float*)d_out;

  char* ws = (char*)d_ws;
  __bf16* xb    = (__bf16*)(ws);                 // [0,8M)  x bf16; later reused as Ab
  __bf16* WqkvT = (__bf16*)(ws + (8u << 20));    // [8M,14M)
  __bf16* WoT   = (__bf16*)(ws + (14u << 20));   // [14M,16M)
  __bf16* QKVb  = (__bf16*)(ws + (16u << 20));   // [16M,40M)  4096x3072 bf16
  __bf16* Vtb   = (__bf16*)(ws + (40u << 20));   // [40M,48M)  1024x4096 bf16
  __bf16* Ab    = xb;

  cvt_f32_bf16<<<4096, 256, 0, stream>>>(x, xb);

  dim3 tb(32, 8);
  dim3 tg(32, 32);
  transpose_cvt<<<tg, tb, 0, stream>>>(Wq, WqkvT);
  transpose_cvt<<<tg, tb, 0, stream>>>(Wk, WqkvT + (size_t)1024 * 1024);
  transpose_cvt<<<tg, tb, 0, stream>>>(Wv, WqkvT + (size_t)2048 * 1024);
  transpose_cvt<<<tg, tb, 0, stream>>>(Wo, WoT);

  gemm_bt<true><<<dim3(L_SEQ / 128, LDQKV / 128), 256, 0, stream>>>(
      xb, WqkvT, QKVb, L_SEQ, LDQKV, C_DIM);

  transpose_v<<<dim3(L_SEQ / 32, C_DIM / 32), tb, 0, stream>>>(QKVb, Vtb);

  attn_fwd<<<512, 256, 0, stream>>>(QKVb, QKVb + 1024, Vtb, Ab);

  gemm_bt<false><<<dim3(L_SEQ / 128, C_DIM / 128), 256, 0, stream>>>(
      Ab, WoT, out, L_SEQ, C_DIM, C_DIM);
}

// Round 4
// 258.559 us; speedup vs baseline: 2.2308x; 1.1134x over previous
//
#include <hip/hip_runtime.h>

// Problem constants (B=1)
#define L_SEQ 4096
#define C_DIM 1024
#define H_NUM 16
#define D_HEAD 64
#define LDQKV 3072

typedef __bf16 bf16x8 __attribute__((ext_vector_type(8)));
typedef __bf16 bf16x4 __attribute__((ext_vector_type(4)));
typedef float f32x4 __attribute__((ext_vector_type(4)));
typedef float f32x16 __attribute__((ext_vector_type(16)));
typedef unsigned int u32;
typedef u32 u32x4 __attribute__((ext_vector_type(4)));

#define AS1 __attribute__((address_space(1)))
#define AS3 __attribute__((address_space(3)))

#define SC_LOG2E 0.1803368801111204f  // 0.125 * log2(e)

__device__ inline __bf16 f2bf(float f) {
  unsigned u = __builtin_bit_cast(unsigned, f);
  u = (u + 0x7fffu + ((u >> 16) & 1u)) >> 16;
  unsigned short s = (unsigned short)u;
  return __builtin_bit_cast(__bf16, s);
}

__device__ inline void gload_lds16(const __bf16* g, __bf16* l) {
  __builtin_amdgcn_global_load_lds((const AS1 void*)g, (AS3 void*)l, 16, 0, 0);
}

// ---------------- x fp32 -> bf16 ----------------
__global__ __launch_bounds__(256) void cvt_f32_bf16(const float* __restrict__ in,
                                                    __bf16* __restrict__ out) {
  int i = (blockIdx.x * 256 + threadIdx.x) * 4;
  float4 v = *(const float4*)(in + i);
  bf16x4 o = {f2bf(v.x), f2bf(v.y), f2bf(v.z), f2bf(v.w)};
  *(bf16x4*)(out + i) = o;
}

// ---------------- 4x W (K x N) fp32 -> Wt (N x K) bf16, fused ----------------
__global__ __launch_bounds__(256) void transpose_cvt4(const float* __restrict__ W0,
                                                      const float* __restrict__ W1,
                                                      const float* __restrict__ W2,
                                                      const float* __restrict__ W3,
                                                      __bf16* __restrict__ dst) {
  __shared__ float t[32][33];
  const int z = blockIdx.z;
  const float* W = (z == 0) ? W0 : (z == 1) ? W1 : (z == 2) ? W2 : W3;
  __bf16* Wt = dst + (size_t)z * 1048576;
  const int tx = threadIdx.x, ty = threadIdx.y;
  const int c0 = blockIdx.x * 32, r0 = blockIdx.y * 32;
#pragma unroll
  for (int k = 0; k < 4; ++k)
    t[ty + k * 8][tx] = W[(size_t)(r0 + ty + k * 8) * C_DIM + c0 + tx];
  __syncthreads();
#pragma unroll
  for (int k = 0; k < 4; ++k)
    Wt[(size_t)(c0 + ty + k * 8) * C_DIM + r0 + tx] = f2bf(t[tx][ty + k * 8]);
}

// ---------------- V slice of QKV -> Vt [C][L] bf16 ----------------
__global__ __launch_bounds__(256) void transpose_v(const __bf16* __restrict__ QKV,
                                                   __bf16* __restrict__ Vt) {
  __shared__ __bf16 t[32][34];
  const int tx = threadIdx.x, ty = threadIdx.y;
  const int q0 = blockIdx.x * 32, c0 = blockIdx.y * 32;
#pragma unroll
  for (int k = 0; k < 4; ++k)
    t[ty + k * 8][tx] = QKV[(size_t)(q0 + ty + k * 8) * LDQKV + 2048 + c0 + tx];
  __syncthreads();
#pragma unroll
  for (int k = 0; k < 4; ++k)
    Vt[(size_t)(c0 + ty + k * 8) * L_SEQ + q0 + tx] = t[tx][ty + k * 8];
}

// ---------------- GEMM: C(MxN) = A(MxK,bf16) * Bt(NxK,bf16)^T ----------------
// cscale applied to output columns < scale_ncols (used to fold attn scale*log2e
// into Q at zero cost).
template <bool OUT_BF16>
__global__ __launch_bounds__(256) void gemm_bt(const __bf16* __restrict__ A,
                                               const __bf16* __restrict__ Bt,
                                               void* __restrict__ Cp,
                                               int M, int N, int K,
                                               float cscale, int scale_ncols) {
  __shared__ __bf16 As[128 * 32];
  __shared__ __bf16 Bs[128 * 32];
  const int tid = threadIdx.x;
  const int lane = tid & 63;
  const int wave = tid >> 6;
  const int wm = wave >> 1, wn = wave & 1;
  const int c16 = lane & 15, g4 = lane >> 4;
  const int srow = lane >> 2, scol = (lane & 3) * 8;

  f32x4 acc[4][4] = {};

  const size_t arow0 = (size_t)blockIdx.x * 128;
  const size_t brow0 = (size_t)blockIdx.y * 128;

  for (int kt = 0; kt < K; kt += 32) {
#pragma unroll
    for (int i = 0; i < 2; ++i) {
      const int row = i * 64 + wave * 16 + srow;
      gload_lds16(A + (arow0 + row) * K + kt + scol, As + (i * 64 + wave * 16) * 32);
      gload_lds16(Bt + (brow0 + row) * K + kt + scol, Bs + (i * 64 + wave * 16) * 32);
    }
    __syncthreads();
    bf16x8 af[4], bfr[4];
#pragma unroll
    for (int mi = 0; mi < 4; ++mi)
      af[mi] = *(const bf16x8*)(As + (wm * 64 + mi * 16 + c16) * 32 + g4 * 8);
#pragma unroll
    for (int ni = 0; ni < 4; ++ni)
      bfr[ni] = *(const bf16x8*)(Bs + (wn * 64 + ni * 16 + c16) * 32 + g4 * 8);
#pragma unroll
    for (int mi = 0; mi < 4; ++mi)
#pragma unroll
      for (int ni = 0; ni < 4; ++ni)
        acc[mi][ni] = __builtin_amdgcn_mfma_f32_16x16x32_bf16(af[mi], bfr[ni], acc[mi][ni], 0, 0, 0);
    __syncthreads();
  }

  const float esc = ((int)brow0 < scale_ncols) ? cscale : 1.0f;
#pragma unroll
  for (int mi = 0; mi < 4; ++mi)
#pragma unroll
    for (int ni = 0; ni < 4; ++ni)
#pragma unroll
      for (int i = 0; i < 4; ++i) {
        size_t row = arow0 + wm * 64 + mi * 16 + g4 * 4 + i;
        size_t col = brow0 + wn * 64 + ni * 16 + c16;
        if (OUT_BF16)
          ((__bf16*)Cp)[row * N + col] = f2bf(acc[mi][ni][i] * esc);
        else
          ((float*)Cp)[row * N + col] = acc[mi][ni][i];
      }
}

// ---------------- causal flash attention, 32x32 swapped-QK^T ------------------
// grid 512: 32 q-tiles of 128 rows (descending) x 16 heads. 4 waves x 32 q.
// S^T = K.Q^T via mfma_32x32x16: lane holds 32 scores of ONE q row -> fully
// in-register softmax (T12). P->bf16 via v_cvt_pk + shfl_xor(32) exchange.
// O^T accumulated in regs; epilogue transposes via swizzled per-warp LDS.
__global__ __launch_bounds__(256, 2) void attn_fwd(const __bf16* __restrict__ Q,
                                                   const __bf16* __restrict__ Kg,
                                                   const __bf16* __restrict__ Vt,
                                                   __bf16* __restrict__ O) {
  const int bid = blockIdx.x;
  const int h = bid & 15;
  const int qt = 31 - (bid >> 4);  // longest blocks dispatch first
  const int nt = 2 * qt + 2;

  __shared__ __bf16 Ks[2][64 * 64];  // [key][d], XOR-swizzled 16B chunks
  __shared__ __bf16 Vs[2][64 * 64];  // [d][key], XOR-swizzled

  const int tid = threadIdx.x;
  const int lane = tid & 63;
  const int wave = tid >> 6;
  const int l31 = lane & 31;
  const int hl = lane >> 5;
  const int qbase = qt * 128 + wave * 32;
  const int q = qbase + l31;             // this lane's q row
  const int kvmax_w = (qbase + 31) >> 6; // last KV tile this warp computes

  const int rl = lane >> 3;
  const int cs = (lane & 7) ^ rl;  // pre-swizzled source chunk

  auto stage = [&](int kv, int b) {
#pragma unroll
    for (int i = 0; i < 2; ++i) {
      const int r = (i * 4 + wave) * 8 + rl;
      gload_lds16(Kg + (size_t)(kv * 64 + r) * LDQKV + h * D_HEAD + cs * 8,
                  &Ks[b][(i * 4 + wave) * 512]);
      gload_lds16(Vt + (size_t)(h * D_HEAD + r) * L_SEQ + kv * 64 + cs * 8,
                  &Vs[b][(i * 4 + wave) * 512]);
    }
  };

  stage(0, 0);

  // Q B-fragments (scale*log2e pre-folded by GEMM epilogue):
  // qf[s][j] = Q[q][s*16 + hl*8 + j]
  bf16x8 qf[4];
  {
    const __bf16* qp = Q + (size_t)q * LDQKV + h * D_HEAD + hl * 8;
#pragma unroll
    for (int s = 0; s < 4; ++s) qf[s] = *(const bf16x8*)(qp + s * 16);
  }

  f32x16 acc0 = {}, acc1 = {};  // O^T[d][q], d-tiles 0/1
  float m = -1e30f, lsum = 0.f;

  int cur = 0;
  for (int kv = 0; kv < nt; ++kv) {
    if (kv + 1 < nt) {
      stage(kv + 1, cur ^ 1);
      asm volatile("s_waitcnt vmcnt(4)" ::: "memory");
    } else {
      asm volatile("s_waitcnt vmcnt(0)" ::: "memory");
    }
    __builtin_amdgcn_sched_barrier(0);
    __builtin_amdgcn_s_barrier();
    __builtin_amdgcn_sched_barrier(0);

    if (kv <= kvmax_w) {
      char* const KsB = (char*)&Ks[cur][0];
      char* const VsB = (char*)&Vs[cur][0];

      // S^T = K . Q^T : lane holds q=l31, key rows kr(reg)+{0,32}
      f32x16 st0 = {}, st1 = {};
      __builtin_amdgcn_s_setprio(1);
#pragma unroll
      for (int s = 0; s < 4; ++s) {
        const int ch = s * 2 + hl;
        bf16x8 a0 = *(const bf16x8*)(KsB + l31 * 128 + ((ch ^ (l31 & 7)) << 4));
        bf16x8 a1 = *(const bf16x8*)(KsB + (32 + l31) * 128 + ((ch ^ (l31 & 7)) << 4));
        st0 = __builtin_amdgcn_mfma_f32_32x32x16_bf16(a0, qf[s], st0, 0, 0, 0);
        st1 = __builtin_amdgcn_mfma_f32_32x32x16_bf16(a1, qf[s], st1, 0, 0, 0);
      }
      __builtin_amdgcn_s_setprio(0);

      // causal mask: only the (always-partial) last tile of this warp
      if (kv == kvmax_w) {
#pragma unroll
        for (int r = 0; r < 16; ++r) {
          const int kr = (r & 3) + 8 * (r >> 2) + 4 * hl;
          const int k0 = kv * 64 + kr;
          st0[r] = (k0 <= q) ? st0[r] : -1e30f;
          st1[r] = (k0 + 32 <= q) ? st1[r] : -1e30f;
        }
      }

      // row max: in-lane tree + one cross-half swap
      float t[16];
#pragma unroll
      for (int r = 0; r < 16; ++r) t[r] = fmaxf(st0[r], st1[r]);
#pragma unroll
      for (int w = 8; w > 0; w >>= 1)
#pragma unroll
        for (int r = 0; r < w; ++r) t[r] = fmaxf(t[r], t[r + w]);
      float mx = fmaxf(t[0], __shfl_xor(t[0], 32, 64));
      const float mnew = fmaxf(m, mx);
      const float corr = exp2f(m - mnew);
      m = mnew;

      // exp2 + row sum
#pragma unroll
      for (int r = 0; r < 16; ++r) {
        st0[r] = exp2f(st0[r] - m);
        st1[r] = exp2f(st1[r] - m);
      }
      float sm[16];
#pragma unroll
      for (int r = 0; r < 16; ++r) sm[r] = st0[r] + st1[r];
#pragma unroll
      for (int w = 8; w > 0; w >>= 1)
#pragma unroll
        for (int r = 0; r < w; ++r) sm[r] = sm[r] + sm[r + w];
      float sl = sm[0] + __shfl_xor(sm[0], 32, 64);
      lsum = lsum * corr + sl;
      acc0 *= corr;
      acc1 *= corr;

      // P -> bf16 pk words (pairs of consecutive keys)
      u32 w0[8], w1[8];
#pragma unroll
      for (int i = 0; i < 8; ++i) {
        asm("v_cvt_pk_bf16_f32 %0, %1, %2" : "=v"(w0[i]) : "v"(st0[2 * i]), "v"(st0[2 * i + 1]));
        asm("v_cvt_pk_bf16_f32 %0, %1, %2" : "=v"(w1[i]) : "v"(st1[2 * i]), "v"(st1[2 * i + 1]));
      }
      // cross-half exchange: one shfl serves both directions
      u32 e0a = (u32)__shfl_xor((int)(hl ? w0[0] : w0[2]), 32, 64);
      u32 e0b = (u32)__shfl_xor((int)(hl ? w0[1] : w0[3]), 32, 64);
      u32 e0c = (u32)__shfl_xor((int)(hl ? w0[4] : w0[6]), 32, 64);
      u32 e0d = (u32)__shfl_xor((int)(hl ? w0[5] : w0[7]), 32, 64);
      u32 e1a = (u32)__shfl_xor((int)(hl ? w1[0] : w1[2]), 32, 64);
      u32 e1b = (u32)__shfl_xor((int)(hl ? w1[1] : w1[3]), 32, 64);
      u32 e1c = (u32)__shfl_xor((int)(hl ? w1[4] : w1[6]), 32, 64);
      u32 e1d = (u32)__shfl_xor((int)(hl ? w1[5] : w1[7]), 32, 64);
      u32x4 f0 = hl ? (u32x4){e0a, e0b, w0[2], w0[3]} : (u32x4){w0[0], w0[1], e0a, e0b};
      u32x4 f1 = hl ? (u32x4){e0c, e0d, w0[6], w0[7]} : (u32x4){w0[4], w0[5], e0c, e0d};
      u32x4 f2 = hl ? (u32x4){e1a, e1b, w1[2], w1[3]} : (u32x4){w1[0], w1[1], e1a, e1b};
      u32x4 f3 = hl ? (u32x4){e1c, e1d, w1[6], w1[7]} : (u32x4){w1[4], w1[5], e1c, e1d};
      bf16x8 pb0 = __builtin_bit_cast(bf16x8, f0);
      bf16x8 pb1 = __builtin_bit_cast(bf16x8, f1);
      bf16x8 pb2 = __builtin_bit_cast(bf16x8, f2);
      bf16x8 pb3 = __builtin_bit_cast(bf16x8, f3);

      // O^T += V^T . P^T
      __builtin_amdgcn_s_setprio(1);
#pragma unroll
      for (int s = 0; s < 4; ++s) {
        const bf16x8 pb = (s == 0) ? pb0 : (s == 1) ? pb1 : (s == 2) ? pb2 : pb3;
        const int ch = s * 2 + hl;
        bf16x8 va0 = *(const bf16x8*)(VsB + l31 * 128 + ((ch ^ (l31 & 7)) << 4));
        bf16x8 va1 = *(const bf16x8*)(VsB + (32 + l31) * 128 + ((ch ^ (l31 & 7)) << 4));
        acc0 = __builtin_amdgcn_mfma_f32_32x32x16_bf16(va0, pb, acc0, 0, 0, 0);
        acc1 = __builtin_amdgcn_mfma_f32_32x32x16_bf16(va1, pb, acc1, 0, 0, 0);
      }
      __builtin_amdgcn_s_setprio(0);
    }

    __builtin_amdgcn_sched_barrier(0);
    __builtin_amdgcn_s_barrier();
    __builtin_amdgcn_sched_barrier(0);
    cur ^= 1;
  }

  // epilogue: normalize, transpose O^T->O via per-warp swizzled LDS, store
  const float rinv = 1.0f / lsum;
  char* const Po = (char*)&Ks[0][0] + wave * 4096;  // 32q x 64d bf16 = 4KB/warp
#pragma unroll
  for (int dt = 0; dt < 2; ++dt) {
#pragma unroll
    for (int i = 0; i < 8; ++i) {
      const int r = 2 * i;
      const int d = dt * 32 + (r & 3) + 8 * (r >> 2) + 4 * hl;
      float lo = (dt ? acc1[r] : acc0[r]) * rinv;
      float hi = (dt ? acc1[r + 1] : acc0[r + 1]) * rinv;
      u32 wv;
      asm("v_cvt_pk_bf16_f32 %0, %1, %2" : "=v"(wv) : "v"(lo), "v"(hi));
      *(u32*)(Po + l31 * 128 + (((d >> 3) ^ (l31 & 7)) << 4) + (d & 7) * 2) = wv;
    }
  }
  asm volatile("s_waitcnt lgkmcnt(0)" ::: "memory");
  __builtin_amdgcn_sched_barrier(0);
#pragma unroll
  for (int j = 0; j < 4; ++j) {
    const int qr = lane >> 1;
    const int c = (lane & 1) * 4 + j;
    bf16x8 ov = *(const bf16x8*)(Po + qr * 128 + ((c ^ (qr & 7)) << 4));
    *(bf16x8*)(O + (size_t)(qbase + qr) * C_DIM + h * D_HEAD + c * 8) = ov;
  }
}

extern "C" void kernel_launch(void* const* d_in, const int* in_sizes, int n_in,
                              void* d_out, int out_size, void* d_ws, size_t ws_size,
                              hipStream_t stream) {
  const float* x = (const float*)d_in[0];
  const float* Wq = (const float*)d_in[1];
  const float* Wk = (const float*)d_in[2];
  const float* Wv = (const float*)d_in[3];
  const float* Wo = (const float*)d_in[4];
  float* out = (float*)d_out;

  char* ws = (char*)d_ws;
  __bf16* xb    = (__bf16*)(ws);                 // [0,8M) x bf16; reused as Ab
  __bf16* WqkvT = (__bf16*)(ws + (8u << 20));    // [8M,14M) 3x1Mi elems; WoT follows
  __bf16* QKVb  = (__bf16*)(ws + (16u << 20));   // [16M,40M) 4096x3072
  __bf16* Vtb   = (__bf16*)(ws + (40u << 20));   // [40M,48M) 1024x4096
  __bf16* WoT   = WqkvT + (size_t)3 * 1048576;   // [14M,16M)
  __bf16* Ab    = xb;

  cvt_f32_bf16<<<4096, 256, 0, stream>>>(x, xb);

  transpose_cvt4<<<dim3(32, 32, 4), dim3(32, 8), 0, stream>>>(Wq, Wk, Wv, Wo, WqkvT);

  // fused QKV projection; Q columns pre-scaled by 0.125*log2(e)
  gemm_bt<true><<<dim3(L_SEQ / 128, LDQKV / 128), 256, 0, stream>>>(
      xb, WqkvT, QKVb, L_SEQ, LDQKV, C_DIM, SC_LOG2E, 1024);

  transpose_v<<<dim3(L_SEQ / 32, C_DIM / 32), dim3(32, 8), 0, stream>>>(QKVb, Vtb);

  attn_fwd<<<512, 256, 0, stream>>>(QKVb, QKVb + 1024, Vtb, Ab);

  gemm_bt<false><<<dim3(L_SEQ / 128, C_DIM / 128), 256, 0, stream>>>(
      Ab, WoT, out, L_SEQ, C_DIM, C_DIM, 1.0f, 0);
}